// Round 7
// baseline (820.221 us; speedup 1.0000x reference)
//
#include <hip/hip_runtime.h>
#include <hip/hip_bf16.h>

#define F_IN  512
#define F_HID 16
#define F_OUT 40
#define CH    8192   // edges per workgroup in bucket pass

typedef __attribute__((ext_vector_type(4))) float f32x4;
typedef __attribute__((ext_vector_type(8))) short s16x8;
typedef unsigned short ushort_t;
typedef unsigned int uint_t;

__device__ __forceinline__ float lof(uint_t v) { return __uint_as_float(v << 16); }
__device__ __forceinline__ float hif(uint_t v) { return __uint_as_float(v & 0xffff0000u); }
__device__ __forceinline__ ushort_t f2bf(float f) {
    __hip_bfloat16 h = __float2bfloat16(f);   // RNE
    union { __hip_bfloat16 h; ushort_t u; } v; v.h = h; return v.u;
}

// ---------------- bucketed CSR build ----------------
// bucket = col >> 9  (512 nodes per bucket, NBUCK <= 256 assumed: N <= 131072)

__global__ __launch_bounds__(1024) void k_bhist(const int* __restrict__ col,
                                                int* __restrict__ bhall, int nE) {
    __shared__ int bh[256];
    int t = threadIdx.x;
    if (t < 256) bh[t] = 0;
    __syncthreads();
    int base = blockIdx.x * CH;
    int end  = min(base + CH, nE);
    for (int e = base + t; e < end; e += 1024)
        atomicAdd(&bh[col[e] >> 9], 1);
    __syncthreads();
    if (t < 256) bhall[blockIdx.x * 256 + t] = bh[t];
}

__global__ void k_bscan2(const int* __restrict__ bhall, int* __restrict__ bstart,
                         int* __restrict__ bcur, int nwge) {
    __shared__ int s[256];
    int t = threadIdx.x;
    int sum = 0;
    for (int w = 0; w < nwge; ++w) sum += bhall[w * 256 + t];
    s[t] = sum;
    __syncthreads();
    for (int off = 1; off < 256; off <<= 1) {
        int v = (t >= off) ? s[t - off] : 0;
        __syncthreads();
        s[t] += v;
        __syncthreads();
    }
    int ex = s[t] - sum;
    bstart[t] = ex;
    bcur[t] = ex;
    if (t == 255) bstart[256] = s[255];
}

__global__ __launch_bounds__(1024) void k_bscatter(const int* __restrict__ row,
                                                   const int* __restrict__ colv,
                                                   int* __restrict__ bcur,
                                                   int* __restrict__ pairs, int nE) {
    __shared__ int colS[CH];
    __shared__ int bh[256];
    __shared__ int lcur[256];
    int t = threadIdx.x;
    if (t < 256) bh[t] = 0;
    __syncthreads();
    int base = blockIdx.x * CH;
    int end  = min(base + CH, nE);
    for (int e = base + t; e < end; e += 1024) {
        int c = colv[e];
        colS[e - base] = c;
        atomicAdd(&bh[c >> 9], 1);
    }
    __syncthreads();
    if (t < 256) {
        int v = bh[t];
        if (v) lcur[t] = atomicAdd(&bcur[t], v);
    }
    __syncthreads();
    for (int e = base + t; e < end; e += 1024) {
        int c = colS[e - base];
        int pos = atomicAdd(&lcur[c >> 9], 1);
        pairs[pos] = (row[e] << 9) | (c & 511);
    }
}

__global__ __launch_bounds__(1024) void k_build(const int* __restrict__ bstart,
                                                const int* __restrict__ pairs,
                                                int* __restrict__ start,
                                                int* __restrict__ csr,
                                                float* __restrict__ dinv,
                                                int n, int nE) {
    __shared__ int h[512];
    __shared__ int s[512];
    __shared__ int cur[512];
    int t = threadIdx.x;
    if (t < 512) h[t] = 0;
    __syncthreads();
    int s0 = bstart[blockIdx.x], s1 = bstart[blockIdx.x + 1];
    for (int e = s0 + t; e < s1; e += 1024)
        atomicAdd(&h[pairs[e] & 511], 1);
    __syncthreads();
    if (t < 512) s[t] = h[t];
    __syncthreads();
    for (int off = 1; off < 512; off <<= 1) {
        int v = 0;
        if (t < 512 && t >= off) v = s[t - off];
        __syncthreads();
        if (t < 512) s[t] += v;
        __syncthreads();
    }
    if (t < 512) {
        int c = h[t];
        int st = s0 + s[t] - c;
        int node = (blockIdx.x << 9) + t;
        if (node < n) {
            start[node] = st;
            dinv[node] = rsqrtf((float)c + 1.0f);
        }
        cur[t] = st;
    }
    if (blockIdx.x == 0 && t == 0) start[n] = nE;
    __syncthreads();
    for (int e = s0 + t; e < s1; e += 1024) {
        int v = pairs[e];
        int pos = atomicAdd(&cur[v & 511], 1);
        csr[pos] = v >> 9;
    }
}

// ---------------- g1 = bf16( dinv * (x @ W1) ) ----------------
__global__ __launch_bounds__(256) void k_xw1(const float* __restrict__ x,
                                             const float* __restrict__ W1,
                                             const float* __restrict__ dinv,
                                             ushort_t* __restrict__ g1b, int n_tiles) {
    int lane = threadIdx.x & 63;
    int wid  = threadIdx.x >> 6;
    int m = lane & 15;
    int g = lane >> 4;

    s16x8 bf[16];
#pragma unroll
    for (int kb = 0; kb < 16; ++kb) {
        union { s16x8 s; unsigned u[4]; } bu;
#pragma unroll
        for (int p = 0; p < 4; ++p) {
            int k0 = kb * 32 + g * 8 + p * 2;
            float lo = W1[(k0 + 0) * F_HID + m];
            float hi = W1[(k0 + 1) * F_HID + m];
            unsigned pk;
            asm("v_cvt_pk_bf16_f32 %0, %1, %2" : "=v"(pk) : "v"(lo), "v"(hi));
            bu.u[p] = pk;
        }
        bf[kb] = bu.s;
    }

    int tile = blockIdx.x * 4 + wid;
    if (tile >= n_tiles) return;

    const float* xr = x + (size_t)(tile * 16 + m) * F_IN + g * 8;
    f32x4 acc = {0.f, 0.f, 0.f, 0.f};
#pragma unroll
    for (int kb = 0; kb < 16; ++kb) {
        f32x4 xa = *(const f32x4*)(xr + kb * 32);
        f32x4 xb = *(const f32x4*)(xr + kb * 32 + 4);
        union { s16x8 s; unsigned u[4]; } au;
        asm("v_cvt_pk_bf16_f32 %0, %1, %2" : "=v"(au.u[0]) : "v"(xa.x), "v"(xa.y));
        asm("v_cvt_pk_bf16_f32 %0, %1, %2" : "=v"(au.u[1]) : "v"(xa.z), "v"(xa.w));
        asm("v_cvt_pk_bf16_f32 %0, %1, %2" : "=v"(au.u[2]) : "v"(xb.x), "v"(xb.y));
        asm("v_cvt_pk_bf16_f32 %0, %1, %2" : "=v"(au.u[3]) : "v"(xb.z), "v"(xb.w));
        acc = __builtin_amdgcn_mfma_f32_16x16x32_bf16(au.s, bf[kb], acc, 0, 0, 0);
    }
#pragma unroll
    for (int p = 0; p < 4; ++p) {
        int rr = tile * 16 + g * 4 + p;
        g1b[(size_t)rr * F_HID + m] = f2bf(acc[p] * dinv[rr]);
    }
}

// ---------------- gather layer 1 (rep-instrumented, idempotent) ----------------
__global__ __launch_bounds__(256) void k_gather1(const int* __restrict__ start,
                                                 const int* __restrict__ csr,
                                                 const uint_t* __restrict__ g1,
                                                 const float* __restrict__ dinv,
                                                 const float* __restrict__ b1,
                                                 uint_t* __restrict__ g2, int n, int rep) {
    int wid = threadIdx.x >> 6, lane = threadIdx.x & 63;
    int node = blockIdx.x * 4 + wid;
    if (node >= n) return;
    int fp = lane & 7, sub = lane >> 3;
    for (int it = 0; it < rep; ++it) {
        int s0 = start[node], s1 = start[node + 1];
        int len = s1 - s0;
        int q = (len + 7) >> 3;
        int e = s0 + sub * q;
        int end = min(e + q, s1);
        float l0 = 0.f, h0 = 0.f, l1 = 0.f, h1 = 0.f, l2 = 0.f, h2 = 0.f, l3 = 0.f, h3 = 0.f;
        for (; e + 4 <= end; e += 4) {
            int r0 = csr[e], r1 = csr[e + 1], r2 = csr[e + 2], r3 = csr[e + 3];
            uint_t v0 = g1[r0 * 8 + fp], v1 = g1[r1 * 8 + fp];
            uint_t v2 = g1[r2 * 8 + fp], v3 = g1[r3 * 8 + fp];
            l0 += lof(v0); h0 += hif(v0);
            l1 += lof(v1); h1 += hif(v1);
            l2 += lof(v2); h2 += hif(v2);
            l3 += lof(v3); h3 += hif(v3);
        }
        for (; e < end; ++e) {
            uint_t v = g1[csr[e] * 8 + fp];
            l0 += lof(v); h0 += hif(v);
        }
        float alo = (l0 + l1) + (l2 + l3);
        float ahi = (h0 + h1) + (h2 + h3);
        alo += __shfl_xor(alo, 8);  ahi += __shfl_xor(ahi, 8);
        alo += __shfl_xor(alo, 16); ahi += __shfl_xor(ahi, 16);
        alo += __shfl_xor(alo, 32); ahi += __shfl_xor(ahi, 32);
        uint_t sv = g1[(size_t)node * 8 + fp];     // self-loop
        alo += lof(sv); ahi += hif(sv);
        float di = dinv[node];
        float2 bb = ((const float2*)b1)[fp];
        float hlo = fmaxf(di * alo + bb.x, 0.f) * di;
        float hhi = fmaxf(di * ahi + bb.y, 0.f) * di;
        if (sub == 0) {
            unsigned pk;
            asm("v_cvt_pk_bf16_f32 %0, %1, %2" : "=v"(pk) : "v"(hlo), "v"(hhi));
            g2[(size_t)node * 8 + fp] = pk;
        }
        asm volatile("" ::: "memory");
    }
}

// ---------------- gather layer 2 + W2 + log_softmax (rep-instrumented, idempotent) ----------------
__global__ __launch_bounds__(256) void k_gather2f(const int* __restrict__ start,
                                                  const int* __restrict__ csr,
                                                  const uint_t* __restrict__ g2,
                                                  const float* __restrict__ dinv,
                                                  const float* __restrict__ W2,
                                                  const float* __restrict__ b2,
                                                  float* __restrict__ out, int n, int rep) {
    int wid = threadIdx.x >> 6, lane = threadIdx.x & 63;
    int node = blockIdx.x * 4 + wid;
    if (node >= n) return;
    int fp = lane & 7, sub = lane >> 3;
    int j = (lane < F_OUT) ? lane : 0;

    float w2c[F_HID];
#pragma unroll
    for (int k = 0; k < F_HID; ++k) w2c[k] = W2[k * F_OUT + j];
    float bj = b2[j];

    for (int it = 0; it < rep; ++it) {
        int s0 = start[node], s1 = start[node + 1];
        int len = s1 - s0;
        int q = (len + 7) >> 3;
        int e = s0 + sub * q;
        int end = min(e + q, s1);
        float l0 = 0.f, h0 = 0.f, l1 = 0.f, h1 = 0.f, l2 = 0.f, h2 = 0.f, l3 = 0.f, h3 = 0.f;
        for (; e + 4 <= end; e += 4) {
            int r0 = csr[e], r1 = csr[e + 1], r2 = csr[e + 2], r3 = csr[e + 3];
            uint_t v0 = g2[r0 * 8 + fp], v1 = g2[r1 * 8 + fp];
            uint_t v2 = g2[r2 * 8 + fp], v3 = g2[r3 * 8 + fp];
            l0 += lof(v0); h0 += hif(v0);
            l1 += lof(v1); h1 += hif(v1);
            l2 += lof(v2); h2 += hif(v2);
            l3 += lof(v3); h3 += hif(v3);
        }
        for (; e < end; ++e) {
            uint_t v = g2[csr[e] * 8 + fp];
            l0 += lof(v); h0 += hif(v);
        }
        float alo = (l0 + l1) + (l2 + l3);
        float ahi = (h0 + h1) + (h2 + h3);
        alo += __shfl_xor(alo, 8);  ahi += __shfl_xor(ahi, 8);
        alo += __shfl_xor(alo, 16); ahi += __shfl_xor(ahi, 16);
        alo += __shfl_xor(alo, 32); ahi += __shfl_xor(ahi, 32);
        uint_t sv = g2[(size_t)node * 8 + fp];     // self-loop
        alo += lof(sv); ahi += hif(sv);
        float di = dinv[node];
        float a_lo = di * alo;
        float a_hi = di * ahi;

        float o = bj;
#pragma unroll
        for (int k = 0; k < F_HID; k += 2) {
            o += __shfl(a_lo, k >> 1) * w2c[k] + __shfl(a_hi, k >> 1) * w2c[k + 1];
        }

        float mo = (lane < F_OUT) ? o : -3.4e38f;
#pragma unroll
        for (int off = 32; off; off >>= 1) mo = fmaxf(mo, __shfl_xor(mo, off));
        float ev = (lane < F_OUT) ? __expf(o - mo) : 0.f;
        float sv2 = ev;
#pragma unroll
        for (int off = 32; off; off >>= 1) sv2 += __shfl_xor(sv2, off);
        float lse = mo + __logf(sv2);
        if (lane < F_OUT) out[(size_t)node * F_OUT + lane] = o - lse;
        asm volatile("" ::: "memory");
    }
}

// ---------------- launcher ----------------

extern "C" void kernel_launch(void* const* d_in, const int* in_sizes, int n_in,
                              void* d_out, int out_size, void* d_ws, size_t ws_size,
                              hipStream_t stream) {
    const float* x  = (const float*)d_in[0];
    const int*   ei = (const int*)d_in[1];
    const float* W1 = (const float*)d_in[2];
    const float* b1 = (const float*)d_in[3];
    const float* W2 = (const float*)d_in[4];
    const float* b2 = (const float*)d_in[5];
    float* out = (float*)d_out;

    const int N = out_size / F_OUT;       // 100000
    const int E = in_sizes[1] / 2;        // 3200000
    const int* row = ei;                  // sources
    const int* col = ei + E;              // targets

    const int NBUCK = (N + 511) >> 9;     // 196
    const int NWGE  = (E + CH - 1) / CH;  // 391
    const int tiles = (N + 15) / 16;
    const int nbT   = (tiles + 3) / 4;
    const int nbG   = (N + 3) / 4;

    const int REP_G1 = 8;    // instrumentation: t1 = (dur - rest - 13*t2)/8 etc.
    const int REP_G2 = 13;

    // workspace layout
    int* bstart   = (int*)d_ws;                 // 260 (NBUCK+1 used)
    int* bcur     = bstart + 260;               // 256
    int* bhall    = bcur + 256;                 // NWGE*256
    int* start    = bhall + NWGE * 256;         // N+4
    int* csr      = start + N + 4;              // E
    int* pairs    = csr + E;                    // E
    float* dinv   = (float*)(pairs + E);        // N
    uint_t* g1    = (uint_t*)(dinv + N);        // 8N dwords (bf16x2 rows)
    uint_t* g2    = g1 + (size_t)N * 8;         // 8N dwords

    k_bhist<<<NWGE, 1024, 0, stream>>>(col, bhall, E);
    k_bscan2<<<1, 256, 0, stream>>>(bhall, bstart, bcur, NWGE);
    k_bscatter<<<NWGE, 1024, 0, stream>>>(row, col, bcur, pairs, E);
    k_build<<<NBUCK, 1024, 0, stream>>>(bstart, pairs, start, csr, dinv, N, E);

    k_xw1<<<nbT, 256, 0, stream>>>(x, W1, dinv, (ushort_t*)g1, tiles);

    k_gather1<<<nbG, 256, 0, stream>>>(start, csr, g1, dinv, b1, g2, N, REP_G1);
    k_gather2f<<<nbG, 256, 0, stream>>>(start, csr, g2, dinv, W2, b2, out, N, REP_G2);
}

// Round 8
// 707.698 us; speedup vs baseline: 1.1590x; 1.1590x over previous
//
#include <hip/hip_runtime.h>
#include <hip/hip_bf16.h>

#define F_IN  512
#define F_HID 16
#define F_OUT 40
#define CH    8192   // edges per workgroup in bucket pass

typedef __attribute__((ext_vector_type(4))) float f32x4;
typedef __attribute__((ext_vector_type(8))) short s16x8;
typedef unsigned short ushort_t;
typedef unsigned int uint_t;

__device__ __forceinline__ float lof(uint_t v) { return __uint_as_float(v << 16); }
__device__ __forceinline__ float hif(uint_t v) { return __uint_as_float(v & 0xffff0000u); }
__device__ __forceinline__ ushort_t f2bf(float f) {
    __hip_bfloat16 h = __float2bfloat16(f);   // RNE
    union { __hip_bfloat16 h; ushort_t u; } v; v.h = h; return v.u;
}

// ---------------- bucketed CSR build ----------------
// bucket = col >> 9  (512 nodes per bucket, NBUCK <= 256 assumed: N <= 131072)

__global__ __launch_bounds__(1024) void k_bhist(const int* __restrict__ col,
                                                int* __restrict__ bhall, int nE, int rep) {
    __shared__ int bh[256];
    int t = threadIdx.x;
    for (int it = 0; it < rep; ++it) {
        if (t < 256) bh[t] = 0;
        __syncthreads();
        int base = blockIdx.x * CH;
        int end  = min(base + CH, nE);
        for (int e = base + t; e < end; e += 1024)
            atomicAdd(&bh[col[e] >> 9], 1);
        __syncthreads();
        if (t < 256) bhall[blockIdx.x * 256 + t] = bh[t];
        __syncthreads();
        asm volatile("" ::: "memory");
    }
}

__global__ void k_bscan2(const int* __restrict__ bhall, int* __restrict__ bstart,
                         int* __restrict__ bcur, int nwge) {
    __shared__ int s[256];
    int t = threadIdx.x;
    int sum = 0;
    for (int w = 0; w < nwge; ++w) sum += bhall[w * 256 + t];
    s[t] = sum;
    __syncthreads();
    for (int off = 1; off < 256; off <<= 1) {
        int v = (t >= off) ? s[t - off] : 0;
        __syncthreads();
        s[t] += v;
        __syncthreads();
    }
    int ex = s[t] - sum;
    bstart[t] = ex;
    bcur[t] = ex;
    if (t == 255) bstart[256] = s[255];
}

__global__ __launch_bounds__(1024) void k_bscatter(const int* __restrict__ row,
                                                   const int* __restrict__ colv,
                                                   int* __restrict__ bcur,
                                                   int* __restrict__ pairs, int nE) {
    __shared__ int colS[CH];
    __shared__ int bh[256];
    __shared__ int lcur[256];
    int t = threadIdx.x;
    if (t < 256) bh[t] = 0;
    __syncthreads();
    int base = blockIdx.x * CH;
    int end  = min(base + CH, nE);
    for (int e = base + t; e < end; e += 1024) {
        int c = colv[e];
        colS[e - base] = c;
        atomicAdd(&bh[c >> 9], 1);
    }
    __syncthreads();
    if (t < 256) {
        int v = bh[t];
        if (v) lcur[t] = atomicAdd(&bcur[t], v);
    }
    __syncthreads();
    for (int e = base + t; e < end; e += 1024) {
        int c = colS[e - base];
        int pos = atomicAdd(&lcur[c >> 9], 1);
        pairs[pos] = (row[e] << 9) | (c & 511);
    }
}

__global__ __launch_bounds__(1024) void k_build(const int* __restrict__ bstart,
                                                const int* __restrict__ pairs,
                                                int* __restrict__ start,
                                                int* __restrict__ csr,
                                                float* __restrict__ dinv,
                                                int n, int nE, int rep) {
    __shared__ int h[512];
    __shared__ int s[512];
    __shared__ int cur[512];
    int t = threadIdx.x;
    for (int it = 0; it < rep; ++it) {
        if (t < 512) h[t] = 0;
        __syncthreads();
        int s0 = bstart[blockIdx.x], s1 = bstart[blockIdx.x + 1];
        for (int e = s0 + t; e < s1; e += 1024)
            atomicAdd(&h[pairs[e] & 511], 1);
        __syncthreads();
        if (t < 512) s[t] = h[t];
        __syncthreads();
        for (int off = 1; off < 512; off <<= 1) {
            int v = 0;
            if (t < 512 && t >= off) v = s[t - off];
            __syncthreads();
            if (t < 512) s[t] += v;
            __syncthreads();
        }
        if (t < 512) {
            int c = h[t];
            int st = s0 + s[t] - c;
            int node = (blockIdx.x << 9) + t;
            if (node < n) {
                start[node] = st;
                dinv[node] = rsqrtf((float)c + 1.0f);
            }
            cur[t] = st;
        }
        if (blockIdx.x == 0 && t == 0) start[n] = nE;
        __syncthreads();
        for (int e = s0 + t; e < s1; e += 1024) {
            int v = pairs[e];
            int pos = atomicAdd(&cur[v & 511], 1);
            csr[pos] = v >> 9;
        }
        __syncthreads();
        asm volatile("" ::: "memory");
    }
}

// ---------------- g1 = bf16( dinv * (x @ W1) ) ----------------
__global__ __launch_bounds__(256) void k_xw1(const float* __restrict__ x,
                                             const float* __restrict__ W1,
                                             const float* __restrict__ dinv,
                                             ushort_t* __restrict__ g1b, int n_tiles, int rep) {
    int lane = threadIdx.x & 63;
    int wid  = threadIdx.x >> 6;
    int m = lane & 15;
    int g = lane >> 4;

    int tile = blockIdx.x * 4 + wid;
    if (tile >= n_tiles) return;

    for (int it = 0; it < rep; ++it) {
        s16x8 bf[16];
#pragma unroll
        for (int kb = 0; kb < 16; ++kb) {
            union { s16x8 s; unsigned u[4]; } bu;
#pragma unroll
            for (int p = 0; p < 4; ++p) {
                int k0 = kb * 32 + g * 8 + p * 2;
                float lo = W1[(k0 + 0) * F_HID + m];
                float hi = W1[(k0 + 1) * F_HID + m];
                unsigned pk;
                asm("v_cvt_pk_bf16_f32 %0, %1, %2" : "=v"(pk) : "v"(lo), "v"(hi));
                bu.u[p] = pk;
            }
            bf[kb] = bu.s;
        }

        const float* xr = x + (size_t)(tile * 16 + m) * F_IN + g * 8;
        f32x4 acc = {0.f, 0.f, 0.f, 0.f};
#pragma unroll
        for (int kb = 0; kb < 16; ++kb) {
            f32x4 xa = *(const f32x4*)(xr + kb * 32);
            f32x4 xb = *(const f32x4*)(xr + kb * 32 + 4);
            union { s16x8 s; unsigned u[4]; } au;
            asm("v_cvt_pk_bf16_f32 %0, %1, %2" : "=v"(au.u[0]) : "v"(xa.x), "v"(xa.y));
            asm("v_cvt_pk_bf16_f32 %0, %1, %2" : "=v"(au.u[1]) : "v"(xa.z), "v"(xa.w));
            asm("v_cvt_pk_bf16_f32 %0, %1, %2" : "=v"(au.u[2]) : "v"(xb.x), "v"(xb.y));
            asm("v_cvt_pk_bf16_f32 %0, %1, %2" : "=v"(au.u[3]) : "v"(xb.z), "v"(xb.w));
            acc = __builtin_amdgcn_mfma_f32_16x16x32_bf16(au.s, bf[kb], acc, 0, 0, 0);
        }
#pragma unroll
        for (int p = 0; p < 4; ++p) {
            int rr = tile * 16 + g * 4 + p;
            g1b[(size_t)rr * F_HID + m] = f2bf(acc[p] * dinv[rr]);
        }
        asm volatile("" ::: "memory");
    }
}

// ---------------- gather layer 1: g2 = bf16( dinv * relu( dinv*(g1[self]+sum g1[in]) + b1 ) ) ----------------
__global__ __launch_bounds__(256) void k_gather1(const int* __restrict__ start,
                                                 const int* __restrict__ csr,
                                                 const uint_t* __restrict__ g1,
                                                 const float* __restrict__ dinv,
                                                 const float* __restrict__ b1,
                                                 uint_t* __restrict__ g2, int n) {
    int wid = threadIdx.x >> 6, lane = threadIdx.x & 63;
    int node = blockIdx.x * 4 + wid;
    if (node >= n) return;
    int fp = lane & 7, sub = lane >> 3;
    int s0 = start[node], s1 = start[node + 1];
    int len = s1 - s0;
    int q = (len + 7) >> 3;
    int e = s0 + sub * q;
    int end = min(e + q, s1);
    float l0 = 0.f, h0 = 0.f, l1 = 0.f, h1 = 0.f, l2 = 0.f, h2 = 0.f, l3 = 0.f, h3 = 0.f;
    for (; e + 4 <= end; e += 4) {
        int r0 = csr[e], r1 = csr[e + 1], r2 = csr[e + 2], r3 = csr[e + 3];
        uint_t v0 = g1[r0 * 8 + fp], v1 = g1[r1 * 8 + fp];
        uint_t v2 = g1[r2 * 8 + fp], v3 = g1[r3 * 8 + fp];
        l0 += lof(v0); h0 += hif(v0);
        l1 += lof(v1); h1 += hif(v1);
        l2 += lof(v2); h2 += hif(v2);
        l3 += lof(v3); h3 += hif(v3);
    }
    for (; e < end; ++e) {
        uint_t v = g1[csr[e] * 8 + fp];
        l0 += lof(v); h0 += hif(v);
    }
    float alo = (l0 + l1) + (l2 + l3);
    float ahi = (h0 + h1) + (h2 + h3);
    alo += __shfl_xor(alo, 8);  ahi += __shfl_xor(ahi, 8);
    alo += __shfl_xor(alo, 16); ahi += __shfl_xor(ahi, 16);
    alo += __shfl_xor(alo, 32); ahi += __shfl_xor(ahi, 32);
    uint_t sv = g1[(size_t)node * 8 + fp];     // self-loop
    alo += lof(sv); ahi += hif(sv);
    float di = dinv[node];
    float2 bb = ((const float2*)b1)[fp];
    float hlo = fmaxf(di * alo + bb.x, 0.f) * di;
    float hhi = fmaxf(di * ahi + bb.y, 0.f) * di;
    if (sub == 0) {
        unsigned pk;
        asm("v_cvt_pk_bf16_f32 %0, %1, %2" : "=v"(pk) : "v"(hlo), "v"(hhi));
        g2[(size_t)node * 8 + fp] = pk;
    }
}

// ---------------- gather layer 2: agg2 = f32( dinv * (g2[self] + sum g2[in]) ) ----------------
__global__ __launch_bounds__(256) void k_gather2(const int* __restrict__ start,
                                                 const int* __restrict__ csr,
                                                 const uint_t* __restrict__ g2,
                                                 const float* __restrict__ dinv,
                                                 float* __restrict__ agg2, int n) {
    int wid = threadIdx.x >> 6, lane = threadIdx.x & 63;
    int node = blockIdx.x * 4 + wid;
    if (node >= n) return;
    int fp = lane & 7, sub = lane >> 3;
    int s0 = start[node], s1 = start[node + 1];
    int len = s1 - s0;
    int q = (len + 7) >> 3;
    int e = s0 + sub * q;
    int end = min(e + q, s1);
    float l0 = 0.f, h0 = 0.f, l1 = 0.f, h1 = 0.f, l2 = 0.f, h2 = 0.f, l3 = 0.f, h3 = 0.f;
    for (; e + 4 <= end; e += 4) {
        int r0 = csr[e], r1 = csr[e + 1], r2 = csr[e + 2], r3 = csr[e + 3];
        uint_t v0 = g2[r0 * 8 + fp], v1 = g2[r1 * 8 + fp];
        uint_t v2 = g2[r2 * 8 + fp], v3 = g2[r3 * 8 + fp];
        l0 += lof(v0); h0 += hif(v0);
        l1 += lof(v1); h1 += hif(v1);
        l2 += lof(v2); h2 += hif(v2);
        l3 += lof(v3); h3 += hif(v3);
    }
    for (; e < end; ++e) {
        uint_t v = g2[csr[e] * 8 + fp];
        l0 += lof(v); h0 += hif(v);
    }
    float alo = (l0 + l1) + (l2 + l3);
    float ahi = (h0 + h1) + (h2 + h3);
    alo += __shfl_xor(alo, 8);  ahi += __shfl_xor(ahi, 8);
    alo += __shfl_xor(alo, 16); ahi += __shfl_xor(ahi, 16);
    alo += __shfl_xor(alo, 32); ahi += __shfl_xor(ahi, 32);
    uint_t sv = g2[(size_t)node * 8 + fp];     // self-loop
    alo += lof(sv); ahi += hif(sv);
    float di = dinv[node];
    if (sub == 0) {
        float2 w; w.x = di * alo; w.y = di * ahi;
        ((float2*)(agg2 + (size_t)node * F_HID))[fp] = w;
    }
}

// ---------------- out = log_softmax(agg2 @ W2 + b2), one node per THREAD, no shfl ----------------
__global__ __launch_bounds__(256) void k_final(const float* __restrict__ agg2,
                                               const float* __restrict__ W2,
                                               const float* __restrict__ b2,
                                               float* __restrict__ out, int n) {
    __shared__ float W2s[F_HID * F_OUT];
    __shared__ float b2s[F_OUT];
    for (int i = threadIdx.x; i < F_HID * F_OUT; i += 256) W2s[i] = W2[i];
    if (threadIdx.x < F_OUT) b2s[threadIdx.x] = b2[threadIdx.x];
    __syncthreads();

    int node = blockIdx.x * 256 + threadIdx.x;
    if (node >= n) return;

    float a[F_HID];
    const f32x4* ap = (const f32x4*)(agg2 + (size_t)node * F_HID);
#pragma unroll
    for (int qq = 0; qq < 4; ++qq) {
        f32x4 v = ap[qq];
        a[qq * 4 + 0] = v.x; a[qq * 4 + 1] = v.y; a[qq * 4 + 2] = v.z; a[qq * 4 + 3] = v.w;
    }

    float o[F_OUT];
#pragma unroll
    for (int j = 0; j < F_OUT; ++j) {
        float acc = b2s[j];
#pragma unroll
        for (int k = 0; k < F_HID; ++k) acc += a[k] * W2s[k * F_OUT + j];
        o[j] = acc;
    }
    float mx = o[0];
#pragma unroll
    for (int j = 1; j < F_OUT; ++j) mx = fmaxf(mx, o[j]);
    float s = 0.f;
#pragma unroll
    for (int j = 0; j < F_OUT; ++j) s += __expf(o[j] - mx);
    float lse = mx + __logf(s);

    float* op = out + (size_t)node * F_OUT;
#pragma unroll
    for (int j = 0; j < F_OUT; ++j) op[j] = o[j] - lse;
}

// ---------------- launcher ----------------

extern "C" void kernel_launch(void* const* d_in, const int* in_sizes, int n_in,
                              void* d_out, int out_size, void* d_ws, size_t ws_size,
                              hipStream_t stream) {
    const float* x  = (const float*)d_in[0];
    const int*   ei = (const int*)d_in[1];
    const float* W1 = (const float*)d_in[2];
    const float* b1 = (const float*)d_in[3];
    const float* W2 = (const float*)d_in[4];
    const float* b2 = (const float*)d_in[5];
    float* out = (float*)d_out;

    const int N = out_size / F_OUT;       // 100000
    const int E = in_sizes[1] / 2;        // 3200000
    const int* row = ei;                  // sources
    const int* col = ei + E;              // targets

    const int NBUCK = (N + 511) >> 9;     // 196
    const int NWGE  = (E + CH - 1) / CH;  // 391
    const int tiles = (N + 15) / 16;
    const int nbT   = (tiles + 3) / 4;
    const int nbG   = (N + 3) / 4;
    const int nbN   = (N + 255) / 256;

    const int REP_BHIST = 15;   // instrumentation: marginal cost = total/rep
    const int REP_BUILD = 10;
    const int REP_XW1   = 5;

    // workspace layout; agg2 aliases pairs (dead after k_build)
    int* bstart   = (int*)d_ws;                 // 260 (NBUCK+1 used)
    int* bcur     = bstart + 260;               // 256
    int* bhall    = bcur + 256;                 // NWGE*256
    int* start    = bhall + NWGE * 256;         // N+4
    int* csr      = start + N + 4;              // E
    int* pairs    = csr + E;                    // E
    float* dinv   = (float*)(pairs + E);        // N
    uint_t* g1    = (uint_t*)(dinv + N);        // 8N dwords (bf16x2 rows)
    uint_t* g2    = g1 + (size_t)N * 8;         // 8N dwords
    float* agg2   = (float*)pairs;              // 16N f32, aliases pairs

    k_bhist<<<NWGE, 1024, 0, stream>>>(col, bhall, E, REP_BHIST);
    k_bscan2<<<1, 256, 0, stream>>>(bhall, bstart, bcur, NWGE);
    k_bscatter<<<NWGE, 1024, 0, stream>>>(row, col, bcur, pairs, E);
    k_build<<<NBUCK, 1024, 0, stream>>>(bstart, pairs, start, csr, dinv, N, E, REP_BUILD);

    k_xw1<<<nbT, 256, 0, stream>>>(x, W1, dinv, (ushort_t*)g1, tiles, REP_XW1);

    k_gather1<<<nbG, 256, 0, stream>>>(start, csr, g1, dinv, b1, g2, N);
    k_gather2<<<nbG, 256, 0, stream>>>(start, csr, g2, dinv, agg2, N);
    k_final<<<nbN, 256, 0, stream>>>(agg2, W2, b2, out, N);
}

// Round 9
// 259.658 us; speedup vs baseline: 3.1588x; 2.7255x over previous
//
#include <hip/hip_runtime.h>
#include <hip/hip_bf16.h>

#define F_IN  512
#define F_HID 16
#define F_OUT 40
#define CH    8192   // edges per workgroup in bucket pass

typedef __attribute__((ext_vector_type(4))) float f32x4;
typedef __attribute__((ext_vector_type(8))) short s16x8;
typedef unsigned short ushort_t;
typedef unsigned int uint_t;

__device__ __forceinline__ float lof(uint_t v) { return __uint_as_float(v << 16); }
__device__ __forceinline__ float hif(uint_t v) { return __uint_as_float(v & 0xffff0000u); }
__device__ __forceinline__ ushort_t f2bf(float f) {
    __hip_bfloat16 h = __float2bfloat16(f);   // RNE
    union { __hip_bfloat16 h; ushort_t u; } v; v.h = h; return v.u;
}

// ---------------- bucketed CSR build ----------------
// bucket = col >> 9  (512 nodes per bucket, NBUCK <= 256 assumed: N <= 131072)

__global__ __launch_bounds__(1024) void k_bhist(const int* __restrict__ col,
                                                int* __restrict__ bhall, int nE) {
    __shared__ int bh[256];
    int t = threadIdx.x;
    if (t < 256) bh[t] = 0;
    __syncthreads();
    int base = blockIdx.x * CH;
    int end  = min(base + CH, nE);
    for (int e = base + t; e < end; e += 1024)
        atomicAdd(&bh[col[e] >> 9], 1);
    __syncthreads();
    if (t < 256) bhall[blockIdx.x * 256 + t] = bh[t];
}

__global__ void k_bscan2(const int* __restrict__ bhall, int* __restrict__ bstart,
                         int* __restrict__ bcur, int nwge) {
    __shared__ int s[256];
    int t = threadIdx.x;
    int sum = 0;
    for (int w = 0; w < nwge; ++w) sum += bhall[w * 256 + t];
    s[t] = sum;
    __syncthreads();
    for (int off = 1; off < 256; off <<= 1) {
        int v = (t >= off) ? s[t - off] : 0;
        __syncthreads();
        s[t] += v;
        __syncthreads();
    }
    int ex = s[t] - sum;
    bstart[t] = ex;
    bcur[t] = ex;
    if (t == 255) bstart[256] = s[255];
}

__global__ __launch_bounds__(1024) void k_bscatter(const int* __restrict__ row,
                                                   const int* __restrict__ colv,
                                                   int* __restrict__ bcur,
                                                   int* __restrict__ pairs, int nE) {
    __shared__ int colS[CH];
    __shared__ int bh[256];
    __shared__ int lcur[256];
    int t = threadIdx.x;
    if (t < 256) bh[t] = 0;
    __syncthreads();
    int base = blockIdx.x * CH;
    int end  = min(base + CH, nE);
    for (int e = base + t; e < end; e += 1024) {
        int c = colv[e];
        colS[e - base] = c;
        atomicAdd(&bh[c >> 9], 1);
    }
    __syncthreads();
    if (t < 256) {
        int v = bh[t];
        if (v) lcur[t] = atomicAdd(&bcur[t], v);
    }
    __syncthreads();
    for (int e = base + t; e < end; e += 1024) {
        int c = colS[e - base];
        int pos = atomicAdd(&lcur[c >> 9], 1);
        pairs[pos] = (row[e] << 9) | (c & 511);
    }
}

__global__ __launch_bounds__(1024) void k_build(const int* __restrict__ bstart,
                                                const int* __restrict__ pairs,
                                                int* __restrict__ start,
                                                int* __restrict__ csr,
                                                float* __restrict__ dinv,
                                                int n, int nE) {
    __shared__ int h[512];
    __shared__ int s[512];
    __shared__ int cur[512];
    int t = threadIdx.x;
    if (t < 512) h[t] = 0;
    __syncthreads();
    int s0 = bstart[blockIdx.x], s1 = bstart[blockIdx.x + 1];
    for (int e = s0 + t; e < s1; e += 1024)
        atomicAdd(&h[pairs[e] & 511], 1);
    __syncthreads();
    if (t < 512) s[t] = h[t];
    __syncthreads();
    for (int off = 1; off < 512; off <<= 1) {
        int v = 0;
        if (t < 512 && t >= off) v = s[t - off];
        __syncthreads();
        if (t < 512) s[t] += v;
        __syncthreads();
    }
    if (t < 512) {
        int c = h[t];
        int st = s0 + s[t] - c;
        int node = (blockIdx.x << 9) + t;
        if (node < n) {
            start[node] = st;
            dinv[node] = rsqrtf((float)c + 1.0f);
        }
        cur[t] = st;
    }
    if (blockIdx.x == 0 && t == 0) start[n] = nE;
    __syncthreads();
    for (int e = s0 + t; e < s1; e += 1024) {
        int v = pairs[e];
        int pos = atomicAdd(&cur[v & 511], 1);
        csr[pos] = v >> 9;
    }
}

// ---------------- g1 = bf16( dinv * (x @ W1) ) ----------------
// W1 staged in XOR-swizzled LDS (bf16, transposed [16 n][512 k]); B-frag = one
// conflict-free ds_read_b128 per kb. Frees ~64 VGPRs vs register-resident W1
// -> 6 waves/SIMD for latency hiding on the x loads (was 3, Occupancy 10%).
__global__ __launch_bounds__(256, 6) void k_xw1(const float* __restrict__ x,
                                                const float* __restrict__ W1,
                                                const float* __restrict__ dinv,
                                                ushort_t* __restrict__ g1b, int n_tiles) {
    __shared__ ushort_t W1t[16 * 512];   // 16 KB, swizzled: elem(n,k) at n*512 + ((blk^(n&7))*8 + k%8), blk=k/8
    int t = threadIdx.x;
    for (int idx = t; idx < 1024; idx += 256) {
        int n = idx & 15, blk = idx >> 4;
        union { s16x8 s; unsigned u[4]; } w;
#pragma unroll
        for (int p = 0; p < 4; ++p) {
            float lo = W1[(blk * 8 + 2 * p + 0) * F_HID + n];
            float hi = W1[(blk * 8 + 2 * p + 1) * F_HID + n];
            asm("v_cvt_pk_bf16_f32 %0, %1, %2" : "=v"(w.u[p]) : "v"(lo), "v"(hi));
        }
        *(s16x8*)&W1t[n * 512 + ((blk ^ (n & 7)) << 3)] = w.s;
    }
    __syncthreads();

    int lane = t & 63;
    int wid  = t >> 6;
    int m = lane & 15;
    int g = lane >> 4;
    int tile = blockIdx.x * 4 + wid;
    if (tile >= n_tiles) return;

    const float* xr = x + (size_t)(tile * 16 + m) * F_IN + g * 8;
    f32x4 acc = {0.f, 0.f, 0.f, 0.f};
#pragma unroll
    for (int kb = 0; kb < 16; ++kb) {
        f32x4 xa = *(const f32x4*)(xr + kb * 32);
        f32x4 xb = *(const f32x4*)(xr + kb * 32 + 4);
        s16x8 bfrag = *(const s16x8*)&W1t[m * 512 + (((kb * 4 + g) ^ (m & 7)) << 3)];
        union { s16x8 s; unsigned u[4]; } au;
        asm("v_cvt_pk_bf16_f32 %0, %1, %2" : "=v"(au.u[0]) : "v"(xa.x), "v"(xa.y));
        asm("v_cvt_pk_bf16_f32 %0, %1, %2" : "=v"(au.u[1]) : "v"(xa.z), "v"(xa.w));
        asm("v_cvt_pk_bf16_f32 %0, %1, %2" : "=v"(au.u[2]) : "v"(xb.x), "v"(xb.y));
        asm("v_cvt_pk_bf16_f32 %0, %1, %2" : "=v"(au.u[3]) : "v"(xb.z), "v"(xb.w));
        acc = __builtin_amdgcn_mfma_f32_16x16x32_bf16(au.s, bfrag, acc, 0, 0, 0);
    }
#pragma unroll
    for (int p = 0; p < 4; ++p) {
        int rr = tile * 16 + g * 4 + p;
        g1b[(size_t)rr * F_HID + m] = f2bf(acc[p] * dinv[rr]);
    }
}

// ---------------- gather layer 1: g2 = bf16( dinv * relu( dinv*(g1[self]+sum g1[in]) + b1 ) ) ----------------
__global__ __launch_bounds__(256) void k_gather1(const int* __restrict__ start,
                                                 const int* __restrict__ csr,
                                                 const uint_t* __restrict__ g1,
                                                 const float* __restrict__ dinv,
                                                 const float* __restrict__ b1,
                                                 uint_t* __restrict__ g2, int n) {
    int wid = threadIdx.x >> 6, lane = threadIdx.x & 63;
    int node = blockIdx.x * 4 + wid;
    if (node >= n) return;
    int fp = lane & 7, sub = lane >> 3;
    int s0 = start[node], s1 = start[node + 1];
    int len = s1 - s0;
    int q = (len + 7) >> 3;
    int e = s0 + sub * q;
    int end = min(e + q, s1);
    float l0 = 0.f, h0 = 0.f, l1 = 0.f, h1 = 0.f, l2 = 0.f, h2 = 0.f, l3 = 0.f, h3 = 0.f;
    for (; e + 4 <= end; e += 4) {
        int r0 = csr[e], r1 = csr[e + 1], r2 = csr[e + 2], r3 = csr[e + 3];
        uint_t v0 = g1[r0 * 8 + fp], v1 = g1[r1 * 8 + fp];
        uint_t v2 = g1[r2 * 8 + fp], v3 = g1[r3 * 8 + fp];
        l0 += lof(v0); h0 += hif(v0);
        l1 += lof(v1); h1 += hif(v1);
        l2 += lof(v2); h2 += hif(v2);
        l3 += lof(v3); h3 += hif(v3);
    }
    for (; e < end; ++e) {
        uint_t v = g1[csr[e] * 8 + fp];
        l0 += lof(v); h0 += hif(v);
    }
    float alo = (l0 + l1) + (l2 + l3);
    float ahi = (h0 + h1) + (h2 + h3);
    alo += __shfl_xor(alo, 8);  ahi += __shfl_xor(ahi, 8);
    alo += __shfl_xor(alo, 16); ahi += __shfl_xor(ahi, 16);
    alo += __shfl_xor(alo, 32); ahi += __shfl_xor(ahi, 32);
    uint_t sv = g1[(size_t)node * 8 + fp];     // self-loop
    alo += lof(sv); ahi += hif(sv);
    float di = dinv[node];
    float2 bb = ((const float2*)b1)[fp];
    float hlo = fmaxf(di * alo + bb.x, 0.f) * di;
    float hhi = fmaxf(di * ahi + bb.y, 0.f) * di;
    if (sub == 0) {
        unsigned pk;
        asm("v_cvt_pk_bf16_f32 %0, %1, %2" : "=v"(pk) : "v"(hlo), "v"(hhi));
        g2[(size_t)node * 8 + fp] = pk;
    }
}

// ---------------- gather layer 2: agg2 = f32( dinv * (g2[self] + sum g2[in]) ) ----------------
__global__ __launch_bounds__(256) void k_gather2(const int* __restrict__ start,
                                                 const int* __restrict__ csr,
                                                 const uint_t* __restrict__ g2,
                                                 const float* __restrict__ dinv,
                                                 float* __restrict__ agg2, int n) {
    int wid = threadIdx.x >> 6, lane = threadIdx.x & 63;
    int node = blockIdx.x * 4 + wid;
    if (node >= n) return;
    int fp = lane & 7, sub = lane >> 3;
    int s0 = start[node], s1 = start[node + 1];
    int len = s1 - s0;
    int q = (len + 7) >> 3;
    int e = s0 + sub * q;
    int end = min(e + q, s1);
    float l0 = 0.f, h0 = 0.f, l1 = 0.f, h1 = 0.f, l2 = 0.f, h2 = 0.f, l3 = 0.f, h3 = 0.f;
    for (; e + 4 <= end; e += 4) {
        int r0 = csr[e], r1 = csr[e + 1], r2 = csr[e + 2], r3 = csr[e + 3];
        uint_t v0 = g2[r0 * 8 + fp], v1 = g2[r1 * 8 + fp];
        uint_t v2 = g2[r2 * 8 + fp], v3 = g2[r3 * 8 + fp];
        l0 += lof(v0); h0 += hif(v0);
        l1 += lof(v1); h1 += hif(v1);
        l2 += lof(v2); h2 += hif(v2);
        l3 += lof(v3); h3 += hif(v3);
    }
    for (; e < end; ++e) {
        uint_t v = g2[csr[e] * 8 + fp];
        l0 += lof(v); h0 += hif(v);
    }
    float alo = (l0 + l1) + (l2 + l3);
    float ahi = (h0 + h1) + (h2 + h3);
    alo += __shfl_xor(alo, 8);  ahi += __shfl_xor(ahi, 8);
    alo += __shfl_xor(alo, 16); ahi += __shfl_xor(ahi, 16);
    alo += __shfl_xor(alo, 32); ahi += __shfl_xor(ahi, 32);
    uint_t sv = g2[(size_t)node * 8 + fp];     // self-loop
    alo += lof(sv); ahi += hif(sv);
    float di = dinv[node];
    if (sub == 0) {
        float2 w; w.x = di * alo; w.y = di * ahi;
        ((float2*)(agg2 + (size_t)node * F_HID))[fp] = w;
    }
}

// ---------------- out = log_softmax(agg2 @ W2 + b2), one node per THREAD, no shfl ----------------
__global__ __launch_bounds__(256) void k_final(const float* __restrict__ agg2,
                                               const float* __restrict__ W2,
                                               const float* __restrict__ b2,
                                               float* __restrict__ out, int n) {
    __shared__ float W2s[F_HID * F_OUT];
    __shared__ float b2s[F_OUT];
    for (int i = threadIdx.x; i < F_HID * F_OUT; i += 256) W2s[i] = W2[i];
    if (threadIdx.x < F_OUT) b2s[threadIdx.x] = b2[threadIdx.x];
    __syncthreads();

    int node = blockIdx.x * 256 + threadIdx.x;
    if (node >= n) return;

    float a[F_HID];
    const f32x4* ap = (const f32x4*)(agg2 + (size_t)node * F_HID);
#pragma unroll
    for (int qq = 0; qq < 4; ++qq) {
        f32x4 v = ap[qq];
        a[qq * 4 + 0] = v.x; a[qq * 4 + 1] = v.y; a[qq * 4 + 2] = v.z; a[qq * 4 + 3] = v.w;
    }

    float o[F_OUT];
#pragma unroll
    for (int j = 0; j < F_OUT; ++j) {
        float acc = b2s[j];
#pragma unroll
        for (int k = 0; k < F_HID; ++k) acc += a[k] * W2s[k * F_OUT + j];
        o[j] = acc;
    }
    float mx = o[0];
#pragma unroll
    for (int j = 1; j < F_OUT; ++j) mx = fmaxf(mx, o[j]);
    float s = 0.f;
#pragma unroll
    for (int j = 0; j < F_OUT; ++j) s += __expf(o[j] - mx);
    float lse = mx + __logf(s);

    float* op = out + (size_t)node * F_OUT;
#pragma unroll
    for (int j = 0; j < F_OUT; ++j) op[j] = o[j] - lse;
}

// ---------------- launcher ----------------

extern "C" void kernel_launch(void* const* d_in, const int* in_sizes, int n_in,
                              void* d_out, int out_size, void* d_ws, size_t ws_size,
                              hipStream_t stream) {
    const float* x  = (const float*)d_in[0];
    const int*   ei = (const int*)d_in[1];
    const float* W1 = (const float*)d_in[2];
    const float* b1 = (const float*)d_in[3];
    const float* W2 = (const float*)d_in[4];
    const float* b2 = (const float*)d_in[5];
    float* out = (float*)d_out;

    const int N = out_size / F_OUT;       // 100000
    const int E = in_sizes[1] / 2;        // 3200000
    const int* row = ei;                  // sources
    const int* col = ei + E;              // targets

    const int NBUCK = (N + 511) >> 9;     // 196
    const int NWGE  = (E + CH - 1) / CH;  // 391
    const int tiles = (N + 15) / 16;
    const int nbT   = (tiles + 3) / 4;
    const int nbG   = (N + 3) / 4;
    const int nbN   = (N + 255) / 256;

    // workspace layout; agg2 aliases pairs (dead after k_build)
    int* bstart   = (int*)d_ws;                 // 260 (NBUCK+1 used)
    int* bcur     = bstart + 260;               // 256
    int* bhall    = bcur + 256;                 // NWGE*256
    int* start    = bhall + NWGE * 256;         // N+4
    int* csr      = start + N + 4;              // E
    int* pairs    = csr + E;                    // E
    float* dinv   = (float*)(pairs + E);        // N
    uint_t* g1    = (uint_t*)(dinv + N);        // 8N dwords (bf16x2 rows)
    uint_t* g2    = g1 + (size_t)N * 8;         // 8N dwords
    float* agg2   = (float*)pairs;              // 16N f32, aliases pairs

    k_bhist<<<NWGE, 1024, 0, stream>>>(col, bhall, E);
    k_bscan2<<<1, 256, 0, stream>>>(bhall, bstart, bcur, NWGE);
    k_bscatter<<<NWGE, 1024, 0, stream>>>(row, col, bcur, pairs, E);
    k_build<<<NBUCK, 1024, 0, stream>>>(bstart, pairs, start, csr, dinv, N, E);

    k_xw1<<<nbT, 256, 0, stream>>>(x, W1, dinv, (ushort_t*)g1, tiles);

    k_gather1<<<nbG, 256, 0, stream>>>(start, csr, g1, dinv, b1, g2, N);
    k_gather2<<<nbG, 256, 0, stream>>>(start, csr, g2, dinv, agg2, N);
    k_final<<<nbN, 256, 0, stream>>>(agg2, W2, b2, out, N);
}